// Round 11
// baseline (191.463 us; speedup 1.0000x reference)
//
#include <hip/hip_runtime.h>
#include <hip/hip_bf16.h>
#include <math.h>

// VOCAB=50000, EMBED=256, MAXLEN=512, UNITS=32, F1=16, BATCH=512.
#define TT 512
#define BB 512
#define EE 256
#define UU 32
#define FF1 16
#define NWAVE 2048            // proj waves (8/CU)
#define RPW 25                // rows per proj wave (2048*25 = 51200 >= 50000)

// tanh(x) = 1 - 2/(e^{2x}+1), branch-free (exp2+rcp HW approx).
__device__ __forceinline__ float fast_tanh(float x) {
    float e = __builtin_amdgcn_exp2f(x * 2.8853900817779268f);  // e^{2x}
    float r = __builtin_amdgcn_rcpf(e + 1.0f);
    return fmaf(-2.0f, r, 1.0f);
}

__device__ __forceinline__ float rdlane(float v, int lane) {
    return __int_as_float(__builtin_amdgcn_readlane(__float_as_int(v), lane));
}

// v += value from lane (i - N) within the 16-lane DPP row (0 past row edge).
#define DPP_ADD(v, ctrl)                                                    \
    (v) += __int_as_float(__builtin_amdgcn_update_dpp(                      \
        0, __float_as_int(v), (ctrl), 0xf, 0xf, true))

// ---------------------------------------------------------------------------
// Kernel A: P[r][u] = emb[r] @ Wx[:,u] + bias[u] — DPP-reduce GEMV v2.
// Changes vs round 10 (which inferred ~49 us):
//  * rows CONSECUTIVE per wave (25-KB streaming chunk, DRAM/L2 locality)
//    instead of 2-MB-strided.
//  * x loads: lane c owns k = kk*64 + 4c + e -> 4 x dwordx4 per row (each
//    instr covers a contiguous 256-B span, 4x g-replicated) instead of 16
//    scalar dwords.
// w preload (one-time, 128 VGPRs): w[kk][e][uu] = Wx[kk*64+4c+e][g*8+uu].
// Reduce over the 16 c-lanes via 4 DPP row_shr stages (VALU pipe, no LDS).
// ---------------------------------------------------------------------------
__global__ __launch_bounds__(64) void proj_dpp2(
    const float* __restrict__ emb, const float* __restrict__ Wx,
    const float* __restrict__ bias, float* __restrict__ P, int nrows)
{
    const int L = threadIdx.x;
    const int g = L >> 4;              // u-octet 0..3
    const int c = L & 15;              // k-lane 0..15
    const int r0 = blockIdx.x * RPW;   // this wave's first row

    // one-time w preload: 32 x float4 (coalesced-ish, one-time cost)
    float w[4][4][8];
    #pragma unroll
    for (int kk = 0; kk < 4; ++kk)
        #pragma unroll
        for (int e = 0; e < 4; ++e) {
            const float4* src = (const float4*)(
                Wx + (size_t)(kk * 64 + c * 4 + e) * UU + g * 8);
            float4 a = src[0], b = src[1];
            w[kk][e][0] = a.x; w[kk][e][1] = a.y;
            w[kk][e][2] = a.z; w[kk][e][3] = a.w;
            w[kk][e][4] = b.x; w[kk][e][5] = b.y;
            w[kk][e][6] = b.z; w[kk][e][7] = b.w;
        }
    float bs[8];
    #pragma unroll
    for (int uu = 0; uu < 8; ++uu) bs[uu] = bias[g * 8 + uu];

    if (r0 >= nrows) return;           // idle tail waves

    auto rowp = [&](int i) {           // clamped row base for loads
        int r = r0 + i; if (r >= nrows) r = nrows - 1;
        return (const float4*)(emb + (size_t)r * EE + c * 4);
    };

    float4 xA[4], xB[4];
    #pragma unroll
    for (int kk = 0; kk < 4; ++kk) xA[kk] = rowp(0)[kk * 16];

    for (int i = 0; i < RPW; ++i) {
        const int r = r0 + i;
        if (r >= nrows) break;
        // prefetch next row (4 dwordx4)
        {
            const float4* rp = rowp(i + 1);
            #pragma unroll
            for (int kk = 0; kk < 4; ++kk) xB[kk] = rp[kk * 16];
        }

        float p[8];
        #pragma unroll
        for (int uu = 0; uu < 8; ++uu) p[uu] = 0.f;
        #pragma unroll
        for (int kk = 0; kk < 4; ++kk) {
            const float xc[4] = {xA[kk].x, xA[kk].y, xA[kk].z, xA[kk].w};
            #pragma unroll
            for (int e = 0; e < 4; ++e) {
                const float xk = xc[e];
                #pragma unroll
                for (int uu = 0; uu < 8; ++uu)
                    p[uu] = fmaf(xk, w[kk][e][uu], p[uu]);
            }
        }

        // reduce over the 16 c-lanes; lane c==15 holds the full sums
        #pragma unroll
        for (int uu = 0; uu < 8; ++uu) {
            DPP_ADD(p[uu], 0x111);   // row_shr:1
            DPP_ADD(p[uu], 0x112);   // row_shr:2
            DPP_ADD(p[uu], 0x114);   // row_shr:4
            DPP_ADD(p[uu], 0x118);   // row_shr:8
        }

        if (c == 15) {
            float4 o0, o1;
            o0.x = p[0] + bs[0]; o0.y = p[1] + bs[1];
            o0.z = p[2] + bs[2]; o0.w = p[3] + bs[3];
            o1.x = p[4] + bs[4]; o1.y = p[5] + bs[5];
            o1.z = p[6] + bs[6]; o1.w = p[7] + bs[7];
            float4* dst = (float4*)(P + (size_t)r * UU + g * 8);
            dst[0] = o0; dst[1] = o1;
        }

        #pragma unroll
        for (int kk = 0; kk < 4; ++kk) xA[kk] = xB[kk];
    }
}

// ---------------------------------------------------------------------------
// Kernel B: h_t = tanh(x_t + h_{t-1} @ Wh); fused heads + sigmoid.
// R6 skeleton (LDS-staged x-stream via gathered global_load_lds) with a
// REWORKED step body: one-OCTET-ahead readlane pipeline (8 broadcasts in
// flight, rdl -> consuming-fma distance >= 16 instrs, covering the
// VALU-writes-SGPR hazard) + 8 independent 4-deep FMA chains.
// ---------------------------------------------------------------------------
__global__ __launch_bounds__(64) void scan_heads(
    const int* __restrict__ tokens, const float* __restrict__ P,
    const float* __restrict__ Wh,
    const float* __restrict__ W1, const float* __restrict__ b1,
    const float* __restrict__ W2, const float* __restrict__ b2,
    float* __restrict__ out)
{
    __shared__ float xs[TT * UU];      // 512 rows x 128 B = 64 KB

    const int L = threadIdx.x;
    const int u = L & 31;
    const int b = blockIdx.x;
    const int* trow = tokens + b * TT;

    float wh[UU];
    #pragma unroll
    for (int k = 0; k < UU; ++k) wh[k] = Wh[k * UU + u];

    // ---- gather phase: 64 global_load_lds instrs, 8 tokens each ----
    const int sub = L >> 3;            // token-within-group
    const int q   = L & 7;             // 16-B chunk within the 128-B row
    for (int c = 0; c < 8; ++c) {
        int tk8[8];
        #pragma unroll
        for (int i = 0; i < 8; ++i)
            tk8[i] = trow[c * 64 + i * 8 + sub];
        #pragma unroll
        for (int i = 0; i < 8; ++i) {
            const float* src = P + (size_t)tk8[i] * UU + q * 4;
            float* dst = xs + (c * 64 + i * 8) * UU;    // wave-uniform base
            __builtin_amdgcn_global_load_lds(
                (const __attribute__((address_space(1))) void*)src,
                (__attribute__((address_space(3))) void*)dst, 16, 0, 0);
        }
    }
    __syncthreads();   // drains vmcnt: all LDS rows resident

    // ---- scan: pure LDS + VALU, octet-pipelined readlanes ----
    float xr[4];
    #pragma unroll
    for (int j = 0; j < 4; ++j) xr[j] = xs[j * UU + u];

    float h = 0.f;

    for (int t = 0; t < TT; t += 4) {
        #pragma unroll
        for (int j = 0; j < 4; ++j) {
            float xn = xs[((t + 4 + j) & (TT - 1)) * UU + u];  // prefetch

            float sA[8], sB[8];
            #pragma unroll
            for (int m = 0; m < 8; ++m) sA[m] = rdlane(h, m);       // oct 0

            float a0 = xr[j], a1 = 0.f, a2 = 0.f, a3 = 0.f;
            float a4 = 0.f, a5 = 0.f, a6 = 0.f, a7 = 0.f;

            #pragma unroll
            for (int m = 0; m < 8; ++m) sB[m] = rdlane(h, 8 + m);   // oct 1
            a0 = fmaf(sA[0], wh[0], a0); a1 = fmaf(sA[1], wh[1], a1);
            a2 = fmaf(sA[2], wh[2], a2); a3 = fmaf(sA[3], wh[3], a3);
            a4 = fmaf(sA[4], wh[4], a4); a5 = fmaf(sA[5], wh[5], a5);
            a6 = fmaf(sA[6], wh[6], a6); a7 = fmaf(sA[7], wh[7], a7);

            #pragma unroll
            for (int m = 0; m < 8; ++m) sA[m] = rdlane(h, 16 + m);  // oct 2
            a0 = fmaf(sB[0], wh[8],  a0); a1 = fmaf(sB[1], wh[9],  a1);
            a2 = fmaf(sB[2], wh[10], a2); a3 = fmaf(sB[3], wh[11], a3);
            a4 = fmaf(sB[4], wh[12], a4); a5 = fmaf(sB[5], wh[13], a5);
            a6 = fmaf(sB[6], wh[14], a6); a7 = fmaf(sB[7], wh[15], a7);

            #pragma unroll
            for (int m = 0; m < 8; ++m) sB[m] = rdlane(h, 24 + m);  // oct 3
            a0 = fmaf(sA[0], wh[16], a0); a1 = fmaf(sA[1], wh[17], a1);
            a2 = fmaf(sA[2], wh[18], a2); a3 = fmaf(sA[3], wh[19], a3);
            a4 = fmaf(sA[4], wh[20], a4); a5 = fmaf(sA[5], wh[21], a5);
            a6 = fmaf(sA[6], wh[22], a6); a7 = fmaf(sA[7], wh[23], a7);

            a0 = fmaf(sB[0], wh[24], a0); a1 = fmaf(sB[1], wh[25], a1);
            a2 = fmaf(sB[2], wh[26], a2); a3 = fmaf(sB[3], wh[27], a3);
            a4 = fmaf(sB[4], wh[28], a4); a5 = fmaf(sB[5], wh[29], a5);
            a6 = fmaf(sB[6], wh[30], a6); a7 = fmaf(sB[7], wh[31], a7);

            h = fast_tanh(((a0 + a1) + (a2 + a3)) + ((a4 + a5) + (a6 + a7)));
            xr[j] = xn;
        }
    }

    // ---- fused heads (once; readlane-only) ----
    const int j = threadIdx.x & 15;
    float s = b1[j];
    #pragma unroll
    for (int k = 0; k < UU; ++k) {
        float hk = rdlane(h, k);
        s = fmaf(hk, W1[k * FF1 + j], s);
    }
    float z = b2[0];
    #pragma unroll
    for (int jj = 0; jj < FF1; ++jj) {
        float yj = rdlane(s, jj);
        z = fmaf(yj, W2[jj], z);
    }
    if (threadIdx.x == 0) {
        float e = __builtin_amdgcn_exp2f(-z * 1.4426950408889634f); // e^{-z}
        out[b] = __builtin_amdgcn_rcpf(1.0f + e);
    }
}

// ---------------------------------------------------------------------------
extern "C" void kernel_launch(void* const* d_in, const int* in_sizes, int n_in,
                              void* d_out, int out_size, void* d_ws, size_t ws_size,
                              hipStream_t stream) {
    const int*   tokens = (const int*)  d_in[0];
    const float* emb    = (const float*)d_in[1];
    const float* Wx     = (const float*)d_in[2];
    const float* Wh     = (const float*)d_in[3];
    const float* bias   = (const float*)d_in[4];
    const float* W1     = (const float*)d_in[5];
    const float* b1     = (const float*)d_in[6];
    const float* W2     = (const float*)d_in[7];
    const float* b2     = (const float*)d_in[8];
    float* out = (float*)d_out;

    const int vocab = in_sizes[1] / EE;        // 50000
    float* P = (float*)d_ws;                   // vocab*32*4 = 6.4 MB

    // A: 2048 single-wave blocks, 25 CONSECUTIVE rows each
    proj_dpp2<<<dim3(NWAVE), dim3(64), 0, stream>>>(
        emb, Wx, bias, P, vocab);

    // B: 1 batch row per wave -> 512 blocks x 64 threads (2 blocks/CU)
    scan_heads<<<dim3(BB), dim3(64), 0, stream>>>(
        tokens, P, Wh, W1, b1, W2, b2, out);
}